// Round 3
// baseline (516.942 us; speedup 1.0000x reference)
//
#include <hip/hip_runtime.h>
#include <hip/hip_bf16.h>

// RGCN fused: per-relation aggregate (gather) -> MFMA GEMM (K=8*64=512).
// Round 8: relation dispatch moved from predicated register FMAs (8x redundant,
// ~21us VALU floor measured r0-r7) to LDS fp32 atomic adds (ds_add_f32):
//  - aggF fp32 [32][520] in LDS; per edge each lane does 4 ds_add_f32 at
//    address (node*520 + rel*64 + 4*c16 + ch) -> HW indexes the relation slot.
//    Bank pattern (stride 520 mod 32 = 8): 2 lanes/bank = conflict-free.
//  - One-shot in-place fp32->bf16 repack into overlaying aggS[32][520]
//    (read-to-regs, barrier, write; pair-rotated chunks, static reg indices).
//  - Quad gather (12 x dwordx4 1KB loads) kept - empirically the right shape.
// LDS 69 KB -> 2 blocks/CU (= measured occupancy of r7, no loss).
// W stays pre-packed as bf16 B-fragments in d_ws (L2-hot), pack_w unchanged.

#define THREADS 512
#define NPB 32            // nodes per block
#define KDIM 512          // NUM_REL * IN_CH
#define LDA 520           // row stride: bf16 elements AND fp32 words
#define MAXE 512          // LDS edge-meta capacity (deg 12 -> 384 used)
#define WFRAG (4 * 16 * 64 * 8)   // 32768 bf16 B-fragment elements

typedef __attribute__((ext_vector_type(8))) short bf16x8;
typedef __attribute__((ext_vector_type(4))) float f32x4;
typedef __attribute__((ext_vector_type(8))) unsigned short u16x8;

extern __shared__ __align__(16) char smem[];

__device__ __forceinline__ unsigned short f2bf(float f) {
  __hip_bfloat16 h = __float2bfloat16(f);
  return *reinterpret_cast<unsigned short*>(&h);
}

// ---- pack W (fp32 or bf16, [512][64]) -> bf16 B-fragment order in ws ----
// frag element i = ((nt*16+kt)*64 + lane)*8 + j  holds  W[kt*32+(lane>>4)*8+j][nt*16+(lane&15)]
__global__ __launch_bounds__(256) void pack_w(const void* __restrict__ wv,
                                              unsigned short* __restrict__ wsB) {
  const int lane = threadIdx.x & 63;
  const unsigned word = ((const unsigned*)wv)[lane];
  const int exf = (int)((word >> 7) & 0xFFu);
  const bool w_bf16 = __popcll(__ballot(exf >= 96 && exf < 160)) >= 48;
  for (int i = blockIdx.x * 256 + threadIdx.x; i < WFRAG; i += gridDim.x * 256) {
    const int j  = i & 7;
    const int l  = (i >> 3) & 63;
    const int kt = (i >> 9) & 15;
    const int nt = i >> 13;
    const int k  = kt * 32 + (l >> 4) * 8 + j;
    const int n  = nt * 16 + (l & 15);
    float v;
    if (w_bf16) v = __bfloat162float(((const __hip_bfloat16*)wv)[k * 64 + n]);
    else        v = ((const float*)wv)[k * 64 + n];
    wsB[i] = f2bf(v);
  }
}

#define ACC_SW(accrow, r, vv)                                        \
  switch (r) {                                                       \
    case 0: accrow[0] += (vv); break; case 1: accrow[1] += (vv); break; \
    case 2: accrow[2] += (vv); break; case 3: accrow[3] += (vv); break; \
    case 4: accrow[4] += (vv); break; case 5: accrow[5] += (vv); break; \
    case 6: accrow[6] += (vv); break; default: accrow[7] += (vv); break; }

__global__ __launch_bounds__(THREADS, 4)
void rgcn_fused(const void* __restrict__ xv,
                const void* __restrict__ wv,
                const int* __restrict__ p32,
                const int* __restrict__ i32,
                const int* __restrict__ t32,
                const unsigned short* __restrict__ wsB,  // null -> W staged in LDS
                float* __restrict__ out,
                int num_nodes) {
  float*          aggF = (float*)smem;                    // [NPB][LDA] fp32
  __hip_bfloat16* aggS = (__hip_bfloat16*)smem;           // [NPB][LDA] bf16 overlay
  __hip_bfloat16* wtS  = (__hip_bfloat16*)(smem + (size_t)NPB * LDA * 4);
  char* tail = smem + (size_t)NPB * LDA * 4 + (wsB ? 0 : (size_t)64 * LDA * 2);
  float*    invS  = (float*)tail;                         // [NPB]
  int*      ptrS  = (int*)(tail + 256);                   // [NPB+1]
  unsigned* eMeta = (unsigned*)(tail + 256 + 144);        // [MAXE]

  const int tid   = threadIdx.x;
  const int lane  = tid & 63;
  const int wvid  = tid >> 6;
  const int node0 = blockIdx.x * NPB;

  // runtime dtype / index-width detection (block-uniform)
  const unsigned xword = ((const unsigned*)xv)[lane];
  const int exf = (int)((xword >> 7) & 0xFFu);
  const bool x_bf16 = __popcll(__ballot(exf >= 96 && exf < 160)) >= 48;
  const bool idx64 = (p32[1] == 0);

  auto ldptr = [&](int n) -> int { return idx64 ? p32[2 * n] : p32[n]; };

  const int ntop   = min(node0 + NPB, num_nodes);
  const int e_lo   = ldptr(node0);
  const int ecount = ldptr(ntop) - e_lo;
  const bool staged = (ecount > 0 && ecount <= MAXE);

  for (int i = tid; i <= NPB; i += THREADS)
    ptrS[i] = ldptr(min(node0 + i, num_nodes));

  if (staged) {
    for (int e = tid; e < ecount; e += THREADS) {
      const int ge = e_lo + e;
      const unsigned s = (unsigned)(idx64 ? i32[2 * ge] : i32[ge]);
      const unsigned r = (unsigned)(idx64 ? t32[2 * ge] : t32[ge]);
      eMeta[e] = s | (r << 24);
    }
  }

  // zero the fp32 accumulator tile (NPB*LDA = 16640 words = 4160 float4)
  {
    f32x4* z = (f32x4*)aggF;
    const f32x4 zero = {0.f, 0.f, 0.f, 0.f};
    for (int i = tid; i < NPB * LDA / 4; i += THREADS) z[i] = zero;
  }

  if (!wsB) {  // fallback: stage W^T in LDS (rare; only if ws too small)
    if (x_bf16) {
      const __hip_bfloat16* wb = (const __hip_bfloat16*)wv;
      for (int i = tid; i < KDIM * 64; i += THREADS)
        wtS[(i & 63) * LDA + (i >> 6)] = wb[i];
    } else {
      const float* wf = (const float*)wv;
      for (int i = tid; i < KDIM * 64; i += THREADS)
        wtS[(i & 63) * LDA + (i >> 6)] = __float2bfloat16(wf[i]);
    }
  }

  __syncthreads();

  // inverse degree (reads ptrS; consumed after repack barriers)
  for (int i = tid; i < NPB; i += THREADS) {
    const int d = ptrS[i + 1] - ptrS[i];
    invS[i] = (d > 0 && node0 + i < num_nodes) ? 1.0f / (float)d : 0.0f;
  }

  const int c16 = lane & 15;
  const int qd  = lane >> 4;

  // ---- gather: wave owns 4 nodes; quad qd owns node nlb+qd ----
  auto gather = [&](auto xp, auto loadrow) {
    const int nlb = wvid * 4;
    const int eq0 = ptrS[nlb + qd] - e_lo;          // quad-uniform per lane
    const int dq  = ptrS[nlb + qd + 1] - e_lo - eq0;
    const bool okfast = staged && (node0 + nlb + 3 < num_nodes) &&
                        (__ballot(dq == 12) == ~0ull);
    if (okfast) {
      // phase 1: edge meta (quad-broadcast LDS reads)
      unsigned m[12];
#pragma unroll
      for (int j = 0; j < 12; ++j) m[j] = eMeta[eq0 + j];
      // phase 2: 12 independent dwordx4 loads (1 KB each), all in flight
      f32x4 v[12];
#pragma unroll
      for (int j = 0; j < 12; ++j)
        v[j] = loadrow((int)(m[j] & 0x00FFFFFFu), c16);
      // phase 3: relation dispatch via LDS fp32 atomic add (ds_add_f32).
      // addr words = (nlb+qd)*520 + rel*64 + 4*c16 + ch -> 2 lanes/bank, free.
      float* qbase = aggF + (size_t)(nlb + qd) * LDA + c16 * 4;
#pragma unroll
      for (int j = 0; j < 12; ++j) {
        float* dst = qbase + ((m[j] >> 24) << 6);
        atomicAdd(dst + 0, v[j][0]);
        atomicAdd(dst + 1, v[j][1]);
        atomicAdd(dst + 2, v[j][2]);
        atomicAdd(dst + 3, v[j][3]);
      }
    } else {
      // generic: full wave per node, lane = channel, wave-uniform switch;
      // sole writer of its rows -> plain fp32 stores (rows pre-zeroed).
#pragma unroll
      for (int t = 0; t < 4; ++t) {
        const int nl = nlb + t;
        float a[8] = {0.f, 0.f, 0.f, 0.f, 0.f, 0.f, 0.f, 0.f};
        if (node0 + nl < num_nodes) {
          const int e0 = ptrS[nl] - e_lo, e1 = ptrS[nl + 1] - e_lo;
          for (int e = e0; e < e1; ++e) {
            unsigned mm;
            if (staged) mm = eMeta[e];
            else {
              const int ge = e_lo + e;
              mm = (unsigned)(idx64 ? i32[2 * ge] : i32[ge]) |
                   ((unsigned)(idx64 ? t32[2 * ge] : t32[ge]) << 24);
            }
            const float vv = (float)xp[(size_t)(mm & 0x00FFFFFFu) * 64 + lane];
            const int r = __builtin_amdgcn_readfirstlane((int)(mm >> 24));
            ACC_SW(a, r, vv)
          }
        }
#pragma unroll
        for (int r = 0; r < 8; ++r)
          aggF[(size_t)nl * LDA + r * 64 + lane] = a[r];
      }
    }
  };

  if (x_bf16) {
    const __hip_bfloat16* xb = (const __hip_bfloat16*)xv;
    auto lr = [&](int src, int c) -> f32x4 {
      const ushort4 u = ((const ushort4*)xv)[(size_t)src * 16 + c];
      f32x4 f;
      f[0] = __uint_as_float((unsigned)(unsigned short)u.x << 16);
      f[1] = __uint_as_float((unsigned)(unsigned short)u.y << 16);
      f[2] = __uint_as_float((unsigned)(unsigned short)u.z << 16);
      f[3] = __uint_as_float((unsigned)(unsigned short)u.w << 16);
      return f;
    };
    gather(xb, lr);
  } else {
    const float* xf = (const float*)xv;
    auto lr = [&](int src, int c) -> f32x4 {
      return ((const f32x4*)xv)[(size_t)src * 16 + c];
    };
    gather(xf, lr);
  }

  __syncthreads();

  // ---- in-place repack: aggF fp32 [32][520] -> aggS bf16 [32][520] ----
  // thread t owns row = t>>4, cols (t&15)*32 .. +31. Read all 32 fp32 into
  // regs (pair-rotated chunks to spread banks), barrier, write 4x16B bf16.
  {
    const int row = tid >> 4;
    const int cb  = (tid & 15) * 32;
    const int rp  = tid & 3;
    f32x4 uA[4], uB[4];
#pragma unroll
    for (int k = 0; k < 4; ++k) {
      const int p = (k + rp) & 3;     // logical chunk-pair (address only)
      const float* src = aggF + (size_t)row * LDA + cb + p * 8;
      uA[k] = *(const f32x4*)(src);
      uB[k] = *(const f32x4*)(src + 4);
    }
    __syncthreads();
#pragma unroll
    for (int k = 0; k < 4; ++k) {
      const int p = (k + rp) & 3;
      u16x8 w;
      w[0] = f2bf(uA[k][0]); w[1] = f2bf(uA[k][1]);
      w[2] = f2bf(uA[k][2]); w[3] = f2bf(uA[k][3]);
      w[4] = f2bf(uB[k][0]); w[5] = f2bf(uB[k][1]);
      w[6] = f2bf(uB[k][2]); w[7] = f2bf(uB[k][3]);
      *(u16x8*)(aggS + (size_t)row * LDA + cb + p * 8) = w;
    }
  }

  __syncthreads();

  // ---- MFMA: out_tile[32x64] = agg[32x512] @ Wcat[512x64] ----
  // 8 waves: mt = wvid>>2 (0..1 row-tiles), nt = wvid&3 (0..3 col-tiles)
  const int mt = wvid >> 2;
  const int nt = wvid & 3;
  const int mi = lane & 15;
  const int q4 = lane >> 4;
  const __hip_bfloat16* ap = aggS + (size_t)(mt * 16 + mi) * LDA + q4 * 8;
  f32x4 c0 = {0.f, 0.f, 0.f, 0.f};
  if (wsB) {
    const bf16x8* B = (const bf16x8*)wsB;
#pragma unroll
    for (int kt = 0; kt < KDIM / 32; ++kt) {
      const bf16x8 a = *(const bf16x8*)(ap + kt * 32);
      const bf16x8 b = B[(nt * 16 + kt) * 64 + lane];
      c0 = __builtin_amdgcn_mfma_f32_16x16x32_bf16(a, b, c0, 0, 0, 0);
    }
  } else {
    const __hip_bfloat16* bp = wtS + (size_t)(nt * 16 + mi) * LDA + q4 * 8;
#pragma unroll
    for (int kt = 0; kt < KDIM / 32; ++kt) {
      const bf16x8 a = *(const bf16x8*)(ap + kt * 32);
      const bf16x8 b = *(const bf16x8*)(bp + kt * 32);
      c0 = __builtin_amdgcn_mfma_f32_16x16x32_bf16(a, b, c0, 0, 0, 0);
    }
  }

  // D layout: col = lane&15, row = q4*4 + reg -> fp32 stores
#pragma unroll
  for (int i = 0; i < 4; ++i) {
    const int row  = q4 * 4 + i;
    const int nl   = mt * 16 + row;
    const int node = node0 + nl;
    if (node < num_nodes) {
      out[(size_t)node * 64 + nt * 16 + mi] = c0[i] * invS[nl];
    }
  }
}

extern "C" void kernel_launch(void* const* d_in, const int* in_sizes, int n_in,
                              void* d_out, int out_size, void* d_ws, size_t ws_size,
                              hipStream_t stream) {
  const void* x   = d_in[0];
  const void* w   = d_in[1];
  const int*  ptr = (const int*)d_in[2];
  const int*  idx = (const int*)d_in[3];
  const int*  et  = (const int*)d_in[4];
  float*      out = (float*)d_out;

  const int num_nodes = in_sizes[0] / 64;   // x is [N, 64]

  const bool useWs = (d_ws != nullptr) &&
                     (ws_size >= (size_t)WFRAG * sizeof(unsigned short));
  unsigned short* wsB = useWs ? (unsigned short*)d_ws : nullptr;
  if (useWs) pack_w<<<32, 256, 0, stream>>>(w, wsB);

  const size_t lds_bytes = (size_t)NPB * LDA * 4 +
                           (useWs ? 0 : (size_t)64 * LDA * 2) +
                           256 + 144 + (size_t)MAXE * 4;

  hipFuncSetAttribute((const void*)rgcn_fused,
                      hipFuncAttributeMaxDynamicSharedMemorySize,
                      (int)lds_bytes);

  const int nblocks = (num_nodes + NPB - 1) / NPB;
  rgcn_fused<<<nblocks, THREADS, lds_bytes, stream>>>(x, w, ptr, idx, et, wsB,
                                                      out, num_nodes);
}

// Round 4
// 131.947 us; speedup vs baseline: 3.9178x; 3.9178x over previous
//
#include <hip/hip_runtime.h>
#include <hip/hip_bf16.h>

// RGCN fused: per-relation aggregate (gather) -> MFMA GEMM (K=8*64=512).
// Round 9: r7's proven structure (quad gather, 12x dwordx4, LDS bf16 agg,
// MFMA epilogue) + relation dispatch via SORT + BOUNDARY FLUSH instead of
// 8x predicated FMA expansion (r7's ~21us VALU floor):
//  - in-LDS stable counting sort of each deg-12 node's edges by relation
//    (nibble-packed counters, static indices, one thread per node).
//  - gather fast path: single running accumulator A; at relation-run
//    boundaries convert+store A to column rel*64 (plain ds_write_b64);
//    non-boundaries store to a per-quad dump slot (addr cndmask, no branch).
//    ~15 ops/edge vs 32. Stable sort -> bit-identical numerics to r7.
//  - agg tile pre-zeroed (covers relations with no edges).
// r8 lesson: LDS fp32 atomicAdd compiles to a CAS loop (NOT ds_add_f32) ->
// 8x regression. Plain stores only.
// W stays pre-packed as bf16 B-fragments in d_ws (L2-hot), pack_w unchanged.

#define THREADS 512
#define NPB 32            // nodes per block
#define KDIM 512          // NUM_REL * IN_CH
#define LDA 520           // padded bf16 row stride (1040 B)
#define MAXE 512          // LDS edge-meta capacity (deg 12 -> 384 used)
#define WFRAG (4 * 16 * 64 * 8)   // 32768 bf16 B-fragment elements

typedef __attribute__((ext_vector_type(8))) short bf16x8;
typedef __attribute__((ext_vector_type(4))) float f32x4;

extern __shared__ __align__(16) char smem[];

__device__ __forceinline__ unsigned short f2bf(float f) {
  __hip_bfloat16 h = __float2bfloat16(f);
  return *reinterpret_cast<unsigned short*>(&h);
}

// ---- pack W (fp32 or bf16, [512][64]) -> bf16 B-fragment order in ws ----
// frag element i = ((nt*16+kt)*64 + lane)*8 + j  holds  W[kt*32+(lane>>4)*8+j][nt*16+(lane&15)]
__global__ __launch_bounds__(256) void pack_w(const void* __restrict__ wv,
                                              unsigned short* __restrict__ wsB) {
  const int lane = threadIdx.x & 63;
  const unsigned word = ((const unsigned*)wv)[lane];
  const int exf = (int)((word >> 7) & 0xFFu);
  const bool w_bf16 = __popcll(__ballot(exf >= 96 && exf < 160)) >= 48;
  for (int i = blockIdx.x * 256 + threadIdx.x; i < WFRAG; i += gridDim.x * 256) {
    const int j  = i & 7;
    const int l  = (i >> 3) & 63;
    const int kt = (i >> 9) & 15;
    const int nt = i >> 13;
    const int k  = kt * 32 + (l >> 4) * 8 + j;
    const int n  = nt * 16 + (l & 15);
    float v;
    if (w_bf16) v = __bfloat162float(((const __hip_bfloat16*)wv)[k * 64 + n]);
    else        v = ((const float*)wv)[k * 64 + n];
    wsB[i] = f2bf(v);
  }
}

#define ACC_SW(accrow, r, vv)                                        \
  switch (r) {                                                       \
    case 0: accrow[0] += (vv); break; case 1: accrow[1] += (vv); break; \
    case 2: accrow[2] += (vv); break; case 3: accrow[3] += (vv); break; \
    case 4: accrow[4] += (vv); break; case 5: accrow[5] += (vv); break; \
    case 6: accrow[6] += (vv); break; default: accrow[7] += (vv); break; }

__global__ __launch_bounds__(THREADS, 6)
void rgcn_fused(const void* __restrict__ xv,
                const void* __restrict__ wv,
                const int* __restrict__ p32,
                const int* __restrict__ i32,
                const int* __restrict__ t32,
                const unsigned short* __restrict__ wsB,  // null -> W staged in LDS
                float* __restrict__ out,
                int num_nodes) {
  // aggS has NPB+1 rows: row NPB is the dump row for non-boundary stores.
  __hip_bfloat16* aggS = (__hip_bfloat16*)smem;                 // [NPB+1][LDA]
  __hip_bfloat16* wtS  = aggS + (NPB + 1) * LDA;                // only if !wsB
  char* tail = smem + (size_t)(NPB + 1) * LDA * 2 +
               (wsB ? 0 : (size_t)64 * LDA * 2);
  float*    invS  = (float*)tail;                               // [NPB]
  int*      ptrS  = (int*)(tail + 256);                         // [NPB+1]
  unsigned* eMeta = (unsigned*)(tail + 256 + 144);              // [MAXE]

  const int tid   = threadIdx.x;
  const int lane  = tid & 63;
  const int wvid  = tid >> 6;
  const int node0 = blockIdx.x * NPB;

  // runtime dtype / index-width detection (block-uniform)
  const unsigned xword = ((const unsigned*)xv)[lane];
  const int exf = (int)((xword >> 7) & 0xFFu);
  const bool x_bf16 = __popcll(__ballot(exf >= 96 && exf < 160)) >= 48;
  const bool idx64 = (p32[1] == 0);

  auto ldptr = [&](int n) -> int { return idx64 ? p32[2 * n] : p32[n]; };

  const int ntop   = min(node0 + NPB, num_nodes);
  const int e_lo   = ldptr(node0);
  const int ecount = ldptr(ntop) - e_lo;
  const bool staged = (ecount > 0 && ecount <= MAXE);

  for (int i = tid; i <= NPB; i += THREADS)
    ptrS[i] = ldptr(min(node0 + i, num_nodes));

  if (staged) {
    for (int e = tid; e < ecount; e += THREADS) {
      const int ge = e_lo + e;
      const unsigned s = (unsigned)(idx64 ? i32[2 * ge] : i32[ge]);
      const unsigned r = (unsigned)(idx64 ? t32[2 * ge] : t32[ge]);
      eMeta[e] = s | (r << 24);
    }
  }

  if (!wsB) {  // fallback: stage W^T in LDS (rare; only if ws too small)
    if (x_bf16) {
      const __hip_bfloat16* wb = (const __hip_bfloat16*)wv;
      for (int i = tid; i < KDIM * 64; i += THREADS)
        wtS[(i & 63) * LDA + (i >> 6)] = wb[i];
    } else {
      const float* wf = (const float*)wv;
      for (int i = tid; i < KDIM * 64; i += THREADS)
        wtS[(i & 63) * LDA + (i >> 6)] = __float2bfloat16(wf[i]);
    }
  }

  __syncthreads();   // eMeta/ptrS staged

  // inverse degree (reads ptrS; consumed after later barriers)
  for (int i = tid; i < NPB; i += THREADS) {
    const int d = ptrS[i + 1] - ptrS[i];
    invS[i] = (d > 0 && node0 + i < num_nodes) ? 1.0f / (float)d : 0.0f;
  }

  // ---- stable counting sort of each deg-12 node's edges by relation ----
  if (staged) {
    for (int n = tid; n < NPB; n += THREADS) {
      const int b0 = ptrS[n] - e_lo;
      const int d  = ptrS[n + 1] - ptrS[n];
      if (d == 12) {
        unsigned mm[12];
        unsigned long long cnt = 0;
#pragma unroll
        for (int i = 0; i < 12; ++i) {
          mm[i] = eMeta[b0 + i];
          cnt += 1ull << ((mm[i] >> 24) * 4);
        }
        unsigned long long off = 0;
        unsigned run = 0;
#pragma unroll
        for (int r = 0; r < 8; ++r) {
          off |= (unsigned long long)run << (r * 4);
          run += (unsigned)((cnt >> (r * 4)) & 15ull);
        }
#pragma unroll
        for (int i = 0; i < 12; ++i) {
          const int sh = (int)(mm[i] >> 24) * 4;
          const unsigned slot = (unsigned)((off >> sh) & 15ull);
          off += 1ull << sh;
          eMeta[b0 + (int)slot] = mm[i];
        }
      }
    }
  }

  // ---- pre-zero agg tile (covers relations with no edges) ----
  {
    f32x4* z = (f32x4*)aggS;
    const f32x4 zero = {0.f, 0.f, 0.f, 0.f};
    const int nvec = (NPB + 1) * LDA * 2 / 16;   // 2145 16B chunks
    for (int i = tid; i < nvec; i += THREADS) z[i] = zero;
  }

  __syncthreads();   // sorted eMeta + zeroed aggS visible

  const int c16 = lane & 15;
  const int qd  = lane >> 4;

  // ---- gather: wave owns 4 nodes (one group); quad qd owns node nlb+qd ----
  auto gather = [&](auto xp, auto loadrow) {
    const int nlb = wvid * 4;
    const int eq0 = ptrS[nlb + qd] - e_lo;          // quad-uniform per lane
    const int dq  = ptrS[nlb + qd + 1] - e_lo - eq0;
    const bool okfast = staged && (node0 + nlb + 3 < num_nodes) &&
                        (__ballot(dq == 12) == ~0ull);
    if (okfast) {
      // phase 1: sorted edge meta (quad-broadcast LDS reads)
      unsigned m[12];
      unsigned rr[12];
#pragma unroll
      for (int j = 0; j < 12; ++j) m[j] = eMeta[eq0 + j];
#pragma unroll
      for (int j = 0; j < 12; ++j) rr[j] = m[j] >> 24;
      // phase 2: 12 independent dwordx4 loads (1 KB each), all in flight
      f32x4 v[12];
#pragma unroll
      for (int j = 0; j < 12; ++j)
        v[j] = loadrow((int)(m[j] & 0x00FFFFFFu), c16);
      // phase 3: run-boundary flush (sorted rels -> runs are contiguous)
      unsigned short* nodeP =
          (unsigned short*)(aggS + (size_t)(nlb + qd) * LDA) + 4 * c16;
      unsigned short* dumpP =
          (unsigned short*)(aggS + (size_t)NPB * LDA) + qd * 136 + 4 * c16;
      f32x4 A = {0.f, 0.f, 0.f, 0.f};
#pragma unroll
      for (int j = 0; j < 12; ++j) {
        A += v[j];
        const bool b = (j == 11) || (rr[j] != rr[j + 1 < 12 ? j + 1 : 11]);
        ushort4 bb;
        bb.x = f2bf(A[0]); bb.y = f2bf(A[1]);
        bb.z = f2bf(A[2]); bb.w = f2bf(A[3]);
        unsigned short* dst = b ? (nodeP + (rr[j] << 6)) : dumpP;
        *(ushort4*)dst = bb;
        A = b ? (f32x4){0.f, 0.f, 0.f, 0.f} : A;
      }
    } else {
      // generic: full wave per node, lane = channel, wave-uniform switch
#pragma unroll
      for (int t = 0; t < 4; ++t) {
        const int nl = nlb + t;
        float a[8] = {0.f, 0.f, 0.f, 0.f, 0.f, 0.f, 0.f, 0.f};
        if (node0 + nl < num_nodes) {
          const int e0 = ptrS[nl] - e_lo, e1 = ptrS[nl + 1] - e_lo;
          for (int e = e0; e < e1; ++e) {
            unsigned mm;
            if (staged) mm = eMeta[e];
            else {
              const int ge = e_lo + e;
              mm = (unsigned)(idx64 ? i32[2 * ge] : i32[ge]) |
                   ((unsigned)(idx64 ? t32[2 * ge] : t32[ge]) << 24);
            }
            const float vv = (float)xp[(size_t)(mm & 0x00FFFFFFu) * 64 + lane];
            const int r = __builtin_amdgcn_readfirstlane((int)(mm >> 24));
            ACC_SW(a, r, vv)
          }
        }
#pragma unroll
        for (int r = 0; r < 8; ++r)
          aggS[(size_t)nl * LDA + r * 64 + lane] = __float2bfloat16(a[r]);
      }
    }
  };

  if (x_bf16) {
    const __hip_bfloat16* xb = (const __hip_bfloat16*)xv;
    auto lr = [&](int src, int c) -> f32x4 {
      const ushort4 u = ((const ushort4*)xv)[(size_t)src * 16 + c];
      f32x4 f;
      f[0] = __uint_as_float((unsigned)(unsigned short)u.x << 16);
      f[1] = __uint_as_float((unsigned)(unsigned short)u.y << 16);
      f[2] = __uint_as_float((unsigned)(unsigned short)u.z << 16);
      f[3] = __uint_as_float((unsigned)(unsigned short)u.w << 16);
      return f;
    };
    gather(xb, lr);
  } else {
    const float* xf = (const float*)xv;
    auto lr = [&](int src, int c) -> f32x4 {
      return ((const f32x4*)xv)[(size_t)src * 16 + c];
    };
    gather(xf, lr);
  }

  __syncthreads();

  // ---- MFMA: out_tile[32x64] = agg[32x512] @ Wcat[512x64] ----
  // 8 waves: mt = wvid>>2 (0..1 row-tiles), nt = wvid&3 (0..3 col-tiles)
  const int mt = wvid >> 2;
  const int nt = wvid & 3;
  const int mi = lane & 15;
  const int q4 = lane >> 4;
  const __hip_bfloat16* ap = aggS + (size_t)(mt * 16 + mi) * LDA + q4 * 8;
  f32x4 c0 = {0.f, 0.f, 0.f, 0.f};
  if (wsB) {
    const bf16x8* B = (const bf16x8*)wsB;
#pragma unroll
    for (int kt = 0; kt < KDIM / 32; ++kt) {
      const bf16x8 a = *(const bf16x8*)(ap + kt * 32);
      const bf16x8 b = B[(nt * 16 + kt) * 64 + lane];
      c0 = __builtin_amdgcn_mfma_f32_16x16x32_bf16(a, b, c0, 0, 0, 0);
    }
  } else {
    const __hip_bfloat16* bp = wtS + (size_t)(nt * 16 + mi) * LDA + q4 * 8;
#pragma unroll
    for (int kt = 0; kt < KDIM / 32; ++kt) {
      const bf16x8 a = *(const bf16x8*)(ap + kt * 32);
      const bf16x8 b = *(const bf16x8*)(bp + kt * 32);
      c0 = __builtin_amdgcn_mfma_f32_16x16x32_bf16(a, b, c0, 0, 0, 0);
    }
  }

  // D layout: col = lane&15, row = q4*4 + reg -> fp32 stores
#pragma unroll
  for (int i = 0; i < 4; ++i) {
    const int row  = q4 * 4 + i;
    const int nl   = mt * 16 + row;
    const int node = node0 + nl;
    if (node < num_nodes) {
      out[(size_t)node * 64 + nt * 16 + mi] = c0[i] * invS[nl];
    }
  }
}

extern "C" void kernel_launch(void* const* d_in, const int* in_sizes, int n_in,
                              void* d_out, int out_size, void* d_ws, size_t ws_size,
                              hipStream_t stream) {
  const void* x   = d_in[0];
  const void* w   = d_in[1];
  const int*  ptr = (const int*)d_in[2];
  const int*  idx = (const int*)d_in[3];
  const int*  et  = (const int*)d_in[4];
  float*      out = (float*)d_out;

  const int num_nodes = in_sizes[0] / 64;   // x is [N, 64]

  const bool useWs = (d_ws != nullptr) &&
                     (ws_size >= (size_t)WFRAG * sizeof(unsigned short));
  unsigned short* wsB = useWs ? (unsigned short*)d_ws : nullptr;
  if (useWs) pack_w<<<32, 256, 0, stream>>>(w, wsB);

  const size_t lds_bytes = (size_t)(NPB + 1) * LDA * 2 +
                           (useWs ? 0 : (size_t)64 * LDA * 2) +
                           256 + 144 + (size_t)MAXE * 4;

  hipFuncSetAttribute((const void*)rgcn_fused,
                      hipFuncAttributeMaxDynamicSharedMemorySize,
                      (int)lds_bytes);

  const int nblocks = (num_nodes + NPB - 1) / NPB;
  rgcn_fused<<<nblocks, THREADS, lds_bytes, stream>>>(x, w, ptr, idx, et, wsB,
                                                      out, num_nodes);
}

// Round 5
// 127.836 us; speedup vs baseline: 4.0438x; 1.0322x over previous
//
#include <hip/hip_runtime.h>
#include <hip/hip_bf16.h>
#include <hip/hip_fp16.h>

// RGCN fused: per-relation aggregate (gather) -> MFMA GEMM (K=8*64=512).
// Round 10: gather bytes halved via fp16 x-cache in workspace.
//  r4 lesson: sort+flush cut VALU 39->22% but time flat at ~54us -> kernel is
//  gather-memory-service bound (164 MB @ ~3 TB/s random-access effective).
//  - pack_x pre-pass: x fp32 [N][64] -> fp16 in d_ws (after W frags).
//    fp16 (not bf16): 2^-11 rel rounding, keeps absmax near current.
//  - fast path gathers 128-B rows (ushort4/lane) + 4x v_cvt_f32_f16.
//  - x working set 25.6 -> 12.8 MB: better L2/L3 fit on top of byte halving.
//  - fallbacks: x-bf16 input -> gather bf16 from xv; small ws -> fp32 path.
// Kept from r4: stable counting sort + run-boundary flush (VALU ~12us-eq),
// quad gather shape (12 loads in flight), LDS bf16 agg, MFMA epilogue.
// r8 lesson: LDS fp32 atomicAdd compiles to a CAS loop. Plain stores only.

#define THREADS 512
#define NPB 32            // nodes per block
#define KDIM 512          // NUM_REL * IN_CH
#define LDA 520           // padded bf16 row stride (1040 B)
#define MAXE 512          // LDS edge-meta capacity (deg 12 -> 384 used)
#define WFRAG (4 * 16 * 64 * 8)   // 32768 bf16 B-fragment elements

typedef __attribute__((ext_vector_type(8))) short bf16x8;
typedef __attribute__((ext_vector_type(4))) float f32x4;
typedef __attribute__((ext_vector_type(8))) unsigned short u16x8;

extern __shared__ __align__(16) char smem[];

__device__ __forceinline__ unsigned short f2bf(float f) {
  __hip_bfloat16 h = __float2bfloat16(f);
  return *reinterpret_cast<unsigned short*>(&h);
}

__device__ __forceinline__ float h2f(unsigned short u) {
  __half h;
  *reinterpret_cast<unsigned short*>(&h) = u;
  return __half2float(h);
}

// ---- pack W (fp32 or bf16, [512][64]) -> bf16 B-fragment order in ws ----
// frag element i = ((nt*16+kt)*64 + lane)*8 + j  holds  W[kt*32+(lane>>4)*8+j][nt*16+(lane&15)]
__global__ __launch_bounds__(256) void pack_w(const void* __restrict__ wv,
                                              unsigned short* __restrict__ wsB) {
  const int lane = threadIdx.x & 63;
  const unsigned word = ((const unsigned*)wv)[lane];
  const int exf = (int)((word >> 7) & 0xFFu);
  const bool w_bf16 = __popcll(__ballot(exf >= 96 && exf < 160)) >= 48;
  for (int i = blockIdx.x * 256 + threadIdx.x; i < WFRAG; i += gridDim.x * 256) {
    const int j  = i & 7;
    const int l  = (i >> 3) & 63;
    const int kt = (i >> 9) & 15;
    const int nt = i >> 13;
    const int k  = kt * 32 + (l >> 4) * 8 + j;
    const int n  = nt * 16 + (l & 15);
    float v;
    if (w_bf16) v = __bfloat162float(((const __hip_bfloat16*)wv)[k * 64 + n]);
    else        v = ((const float*)wv)[k * 64 + n];
    wsB[i] = f2bf(v);
  }
}

// ---- pack x: fp32 [N][64] -> fp16 cache in ws (skip if x already bf16) ----
__global__ __launch_bounds__(256) void pack_x(const void* __restrict__ xv,
                                              unsigned short* __restrict__ wsX,
                                              int total8) {   // = N*8
  const int lane = threadIdx.x & 63;
  const unsigned word = ((const unsigned*)xv)[lane];
  const int exf = (int)((word >> 7) & 0xFFu);
  const bool x_bf16 = __popcll(__ballot(exf >= 96 && exf < 160)) >= 48;
  if (x_bf16) return;   // main kernel gathers bf16 directly from xv
  const f32x4* xf = (const f32x4*)xv;
  for (int i = blockIdx.x * 256 + threadIdx.x; i < total8; i += gridDim.x * 256) {
    const f32x4 a = xf[i * 2 + 0];
    const f32x4 b = xf[i * 2 + 1];
    u16x8 o;
    __half h;
    h = __float2half(a[0]); o[0] = *reinterpret_cast<unsigned short*>(&h);
    h = __float2half(a[1]); o[1] = *reinterpret_cast<unsigned short*>(&h);
    h = __float2half(a[2]); o[2] = *reinterpret_cast<unsigned short*>(&h);
    h = __float2half(a[3]); o[3] = *reinterpret_cast<unsigned short*>(&h);
    h = __float2half(b[0]); o[4] = *reinterpret_cast<unsigned short*>(&h);
    h = __float2half(b[1]); o[5] = *reinterpret_cast<unsigned short*>(&h);
    h = __float2half(b[2]); o[6] = *reinterpret_cast<unsigned short*>(&h);
    h = __float2half(b[3]); o[7] = *reinterpret_cast<unsigned short*>(&h);
    ((u16x8*)wsX)[i] = o;
  }
}

#define ACC_SW(accrow, r, vv)                                        \
  switch (r) {                                                       \
    case 0: accrow[0] += (vv); break; case 1: accrow[1] += (vv); break; \
    case 2: accrow[2] += (vv); break; case 3: accrow[3] += (vv); break; \
    case 4: accrow[4] += (vv); break; case 5: accrow[5] += (vv); break; \
    case 6: accrow[6] += (vv); break; default: accrow[7] += (vv); break; }

__global__ __launch_bounds__(THREADS, 6)
void rgcn_fused(const void* __restrict__ xv,
                const void* __restrict__ wv,
                const int* __restrict__ p32,
                const int* __restrict__ i32,
                const int* __restrict__ t32,
                const unsigned short* __restrict__ wsB,  // null -> W staged in LDS
                const unsigned short* __restrict__ wsX,  // fp16 x cache (or null)
                float* __restrict__ out,
                int num_nodes) {
  // aggS has NPB+1 rows: row NPB is the dump row for non-boundary stores.
  __hip_bfloat16* aggS = (__hip_bfloat16*)smem;                 // [NPB+1][LDA]
  __hip_bfloat16* wtS  = aggS + (NPB + 1) * LDA;                // only if !wsB
  char* tail = smem + (size_t)(NPB + 1) * LDA * 2 +
               (wsB ? 0 : (size_t)64 * LDA * 2);
  float*    invS  = (float*)tail;                               // [NPB]
  int*      ptrS  = (int*)(tail + 256);                         // [NPB+1]
  unsigned* eMeta = (unsigned*)(tail + 256 + 144);              // [MAXE]

  const int tid   = threadIdx.x;
  const int lane  = tid & 63;
  const int wvid  = tid >> 6;
  const int node0 = blockIdx.x * NPB;

  // runtime dtype / index-width detection (block-uniform)
  const unsigned xword = ((const unsigned*)xv)[lane];
  const int exf = (int)((xword >> 7) & 0xFFu);
  const bool x_bf16 = __popcll(__ballot(exf >= 96 && exf < 160)) >= 48;
  const bool idx64 = (p32[1] == 0);

  auto ldptr = [&](int n) -> int { return idx64 ? p32[2 * n] : p32[n]; };

  const int ntop   = min(node0 + NPB, num_nodes);
  const int e_lo   = ldptr(node0);
  const int ecount = ldptr(ntop) - e_lo;
  const bool staged = (ecount > 0 && ecount <= MAXE);

  for (int i = tid; i <= NPB; i += THREADS)
    ptrS[i] = ldptr(min(node0 + i, num_nodes));

  if (staged) {
    for (int e = tid; e < ecount; e += THREADS) {
      const int ge = e_lo + e;
      const unsigned s = (unsigned)(idx64 ? i32[2 * ge] : i32[ge]);
      const unsigned r = (unsigned)(idx64 ? t32[2 * ge] : t32[ge]);
      eMeta[e] = s | (r << 24);
    }
  }

  if (!wsB) {  // fallback: stage W^T in LDS (rare; only if ws too small)
    if (x_bf16) {
      const __hip_bfloat16* wb = (const __hip_bfloat16*)wv;
      for (int i = tid; i < KDIM * 64; i += THREADS)
        wtS[(i & 63) * LDA + (i >> 6)] = wb[i];
    } else {
      const float* wf = (const float*)wv;
      for (int i = tid; i < KDIM * 64; i += THREADS)
        wtS[(i & 63) * LDA + (i >> 6)] = __float2bfloat16(wf[i]);
    }
  }

  __syncthreads();   // eMeta/ptrS staged

  // inverse degree (reads ptrS; consumed after later barriers)
  for (int i = tid; i < NPB; i += THREADS) {
    const int d = ptrS[i + 1] - ptrS[i];
    invS[i] = (d > 0 && node0 + i < num_nodes) ? 1.0f / (float)d : 0.0f;
  }

  // ---- stable counting sort of each deg-12 node's edges by relation ----
  if (staged) {
    for (int n = tid; n < NPB; n += THREADS) {
      const int b0 = ptrS[n] - e_lo;
      const int d  = ptrS[n + 1] - ptrS[n];
      if (d == 12) {
        unsigned mm[12];
        unsigned long long cnt = 0;
#pragma unroll
        for (int i = 0; i < 12; ++i) {
          mm[i] = eMeta[b0 + i];
          cnt += 1ull << ((mm[i] >> 24) * 4);
        }
        unsigned long long off = 0;
        unsigned run = 0;
#pragma unroll
        for (int r = 0; r < 8; ++r) {
          off |= (unsigned long long)run << (r * 4);
          run += (unsigned)((cnt >> (r * 4)) & 15ull);
        }
#pragma unroll
        for (int i = 0; i < 12; ++i) {
          const int sh = (int)(mm[i] >> 24) * 4;
          const unsigned slot = (unsigned)((off >> sh) & 15ull);
          off += 1ull << sh;
          eMeta[b0 + (int)slot] = mm[i];
        }
      }
    }
  }

  // ---- pre-zero agg tile (covers relations with no edges) ----
  {
    f32x4* z = (f32x4*)aggS;
    const f32x4 zero = {0.f, 0.f, 0.f, 0.f};
    const int nvec = (NPB + 1) * LDA * 2 / 16;   // 16B chunks
    for (int i = tid; i < nvec; i += THREADS) z[i] = zero;
  }

  __syncthreads();   // sorted eMeta + zeroed aggS visible

  const int c16 = lane & 15;
  const int qd  = lane >> 4;

  // ---- gather: wave owns 4 nodes (one group); quad qd owns node nlb+qd ----
  auto gather = [&](auto xp, auto loadrow) {
    const int nlb = wvid * 4;
    const int eq0 = ptrS[nlb + qd] - e_lo;          // quad-uniform per lane
    const int dq  = ptrS[nlb + qd + 1] - e_lo - eq0;
    const bool okfast = staged && (node0 + nlb + 3 < num_nodes) &&
                        (__ballot(dq == 12) == ~0ull);
    if (okfast) {
      // phase 1: sorted edge meta (quad-broadcast LDS reads)
      unsigned m[12];
      unsigned rr[12];
#pragma unroll
      for (int j = 0; j < 12; ++j) m[j] = eMeta[eq0 + j];
#pragma unroll
      for (int j = 0; j < 12; ++j) rr[j] = m[j] >> 24;
      // phase 2: 12 independent row loads, all in flight
      f32x4 v[12];
#pragma unroll
      for (int j = 0; j < 12; ++j)
        v[j] = loadrow((int)(m[j] & 0x00FFFFFFu), c16);
      // phase 3: run-boundary flush (sorted rels -> runs are contiguous)
      unsigned short* nodeP =
          (unsigned short*)(aggS + (size_t)(nlb + qd) * LDA) + 4 * c16;
      unsigned short* dumpP =
          (unsigned short*)(aggS + (size_t)NPB * LDA) + qd * 136 + 4 * c16;
      f32x4 A = {0.f, 0.f, 0.f, 0.f};
#pragma unroll
      for (int j = 0; j < 12; ++j) {
        A += v[j];
        const bool b = (j == 11) || (rr[j] != rr[j + 1 < 12 ? j + 1 : 11]);
        ushort4 bb;
        bb.x = f2bf(A[0]); bb.y = f2bf(A[1]);
        bb.z = f2bf(A[2]); bb.w = f2bf(A[3]);
        unsigned short* dst = b ? (nodeP + (rr[j] << 6)) : dumpP;
        *(ushort4*)dst = bb;
        A = b ? (f32x4){0.f, 0.f, 0.f, 0.f} : A;
      }
    } else {
      // generic: full wave per node, lane = channel, wave-uniform switch
#pragma unroll
      for (int t = 0; t < 4; ++t) {
        const int nl = nlb + t;
        float a[8] = {0.f, 0.f, 0.f, 0.f, 0.f, 0.f, 0.f, 0.f};
        if (node0 + nl < num_nodes) {
          const int e0 = ptrS[nl] - e_lo, e1 = ptrS[nl + 1] - e_lo;
          for (int e = e0; e < e1; ++e) {
            unsigned mm;
            if (staged) mm = eMeta[e];
            else {
              const int ge = e_lo + e;
              mm = (unsigned)(idx64 ? i32[2 * ge] : i32[ge]) |
                   ((unsigned)(idx64 ? t32[2 * ge] : t32[ge]) << 24);
            }
            const float vv = xp((size_t)(mm & 0x00FFFFFFu) * 64 + lane);
            const int r = __builtin_amdgcn_readfirstlane((int)(mm >> 24));
            ACC_SW(a, r, vv)
          }
        }
#pragma unroll
        for (int r = 0; r < 8; ++r)
          aggS[(size_t)nl * LDA + r * 64 + lane] = __float2bfloat16(a[r]);
      }
    }
  };

  if (!x_bf16 && wsX) {
    // fp16 x-cache path: 128-B rows, ushort4/lane + 4x cvt
    auto xp = [&](size_t i) -> float { return h2f(wsX[i]); };
    auto lr = [&](int src, int c) -> f32x4 {
      const ushort4 u = ((const ushort4*)wsX)[(size_t)src * 16 + c];
      f32x4 f;
      f[0] = h2f(u.x); f[1] = h2f(u.y); f[2] = h2f(u.z); f[3] = h2f(u.w);
      return f;
    };
    gather(xp, lr);
  } else if (x_bf16) {
    auto xp = [&](size_t i) -> float {
      const unsigned short u = ((const unsigned short*)xv)[i];
      return __uint_as_float((unsigned)u << 16);
    };
    auto lr = [&](int src, int c) -> f32x4 {
      const ushort4 u = ((const ushort4*)xv)[(size_t)src * 16 + c];
      f32x4 f;
      f[0] = __uint_as_float((unsigned)(unsigned short)u.x << 16);
      f[1] = __uint_as_float((unsigned)(unsigned short)u.y << 16);
      f[2] = __uint_as_float((unsigned)(unsigned short)u.z << 16);
      f[3] = __uint_as_float((unsigned)(unsigned short)u.w << 16);
      return f;
    };
    gather(xp, lr);
  } else {
    auto xp = [&](size_t i) -> float { return ((const float*)xv)[i]; };
    auto lr = [&](int src, int c) -> f32x4 {
      return ((const f32x4*)xv)[(size_t)src * 16 + c];
    };
    gather(xp, lr);
  }

  __syncthreads();

  // ---- MFMA: out_tile[32x64] = agg[32x512] @ Wcat[512x64] ----
  // 8 waves: mt = wvid>>2 (0..1 row-tiles), nt = wvid&3 (0..3 col-tiles)
  const int mt = wvid >> 2;
  const int nt = wvid & 3;
  const int mi = lane & 15;
  const int q4 = lane >> 4;
  const __hip_bfloat16* ap = aggS + (size_t)(mt * 16 + mi) * LDA + q4 * 8;
  f32x4 c0 = {0.f, 0.f, 0.f, 0.f};
  if (wsB) {
    const bf16x8* B = (const bf16x8*)wsB;
#pragma unroll
    for (int kt = 0; kt < KDIM / 32; ++kt) {
      const bf16x8 a = *(const bf16x8*)(ap + kt * 32);
      const bf16x8 b = B[(nt * 16 + kt) * 64 + lane];
      c0 = __builtin_amdgcn_mfma_f32_16x16x32_bf16(a, b, c0, 0, 0, 0);
    }
  } else {
    const __hip_bfloat16* bp = wtS + (size_t)(nt * 16 + mi) * LDA + q4 * 8;
#pragma unroll
    for (int kt = 0; kt < KDIM / 32; ++kt) {
      const bf16x8 a = *(const bf16x8*)(ap + kt * 32);
      const bf16x8 b = *(const bf16x8*)(bp + kt * 32);
      c0 = __builtin_amdgcn_mfma_f32_16x16x32_bf16(a, b, c0, 0, 0, 0);
    }
  }

  // D layout: col = lane&15, row = q4*4 + reg -> fp32 stores
#pragma unroll
  for (int i = 0; i < 4; ++i) {
    const int row  = q4 * 4 + i;
    const int nl   = mt * 16 + row;
    const int node = node0 + nl;
    if (node < num_nodes) {
      out[(size_t)node * 64 + nt * 16 + mi] = c0[i] * invS[nl];
    }
  }
}

extern "C" void kernel_launch(void* const* d_in, const int* in_sizes, int n_in,
                              void* d_out, int out_size, void* d_ws, size_t ws_size,
                              hipStream_t stream) {
  const void* x   = d_in[0];
  const void* w   = d_in[1];
  const int*  ptr = (const int*)d_in[2];
  const int*  idx = (const int*)d_in[3];
  const int*  et  = (const int*)d_in[4];
  float*      out = (float*)d_out;

  const int num_nodes = in_sizes[0] / 64;   // x is [N, 64]

  const size_t needW = (size_t)WFRAG * sizeof(unsigned short);   // 64 KB
  const size_t needX = needW + (size_t)num_nodes * 64 * 2;       // + N*128 B
  const bool useWs = (d_ws != nullptr) && (ws_size >= needW);
  const bool useX  = (d_ws != nullptr) && (ws_size >= needX);
  unsigned short* wsB = useWs ? (unsigned short*)d_ws : nullptr;
  unsigned short* wsX = useX ? (unsigned short*)((char*)d_ws + needW) : nullptr;

  if (useWs) pack_w<<<32, 256, 0, stream>>>(w, wsB);
  if (useX)  pack_x<<<1024, 256, 0, stream>>>(x, wsX, num_nodes * 8);

  const size_t lds_bytes = (size_t)(NPB + 1) * LDA * 2 +
                           (useWs ? 0 : (size_t)64 * LDA * 2) +
                           256 + 144 + (size_t)MAXE * 4;

  hipFuncSetAttribute((const void*)rgcn_fused,
                      hipFuncAttributeMaxDynamicSharedMemorySize,
                      (int)lds_bytes);

  const int nblocks = (num_nodes + NPB - 1) / NPB;
  rgcn_fused<<<nblocks, THREADS, lds_bytes, stream>>>(x, w, ptr, idx, et, wsB,
                                                      wsX, out, num_nodes);
}

// Round 6
// 124.742 us; speedup vs baseline: 4.1441x; 1.0248x over previous
//
#include <hip/hip_runtime.h>
#include <hip/hip_bf16.h>
#include <hip/hip_fp16.h>

// RGCN fused: per-relation aggregate (gather) -> MFMA GEMM (K=8*64=512).
// Round 11: meta pre-pack + unified pack kernel + non-temporal traffic hints.
//  r5 result: fp16 x-cache halved gather bytes (FETCH 135->64 MB), steady main
//  ~43us. Remaining reducible FETCH is the int64 idx/et meta stream (19.2 MB,
//  strided 4-of-8-byte reads in the serial staging prologue).
//  - pack_all (one kernel): W bf16 B-frags + meta u32 (idx|rel<<24, 4.8 MB)
//    + x fp16 cache. Main staging = one coalesced dword/edge (-14.4 MB FETCH).
//  - out stores + meta loads are non-temporal: write-once/read-once streams
//    no longer evict the 12.8 MB x-cache from L2.
// Kept: stable counting sort + run-boundary flush (r4, VALU 39->22%), quad
// gather 12x loads in flight (r7-shape), fp16 x-cache (r5), LDS bf16 agg,
// MFMA epilogue. r8 lesson: LDS fp32 atomicAdd = CAS loop, plain stores only.

#define THREADS 512
#define NPB 32            // nodes per block
#define KDIM 512          // NUM_REL * IN_CH
#define LDA 520           // padded bf16 row stride (1040 B)
#define MAXE 512          // LDS edge-meta capacity (deg 12 -> 384 used)
#define WFRAG (4 * 16 * 64 * 8)   // 32768 bf16 B-fragment elements

typedef __attribute__((ext_vector_type(8))) short bf16x8;
typedef __attribute__((ext_vector_type(4))) float f32x4;
typedef __attribute__((ext_vector_type(8))) unsigned short u16x8;

extern __shared__ __align__(16) char smem[];

__device__ __forceinline__ unsigned short f2bf(float f) {
  __hip_bfloat16 h = __float2bfloat16(f);
  return *reinterpret_cast<unsigned short*>(&h);
}

__device__ __forceinline__ float h2f(unsigned short u) {
  __half h;
  *reinterpret_cast<unsigned short*>(&h) = u;
  return __half2float(h);
}

// ---- unified pre-pack: W -> bf16 B-frags, idx/et -> u32 meta, x -> fp16 ----
// W frag element i = ((nt*16+kt)*64 + lane)*8 + j
//   holds W[kt*32+(lane>>4)*8+j][nt*16+(lane&15)]
__global__ __launch_bounds__(256)
void pack_all(const void* __restrict__ xv, const void* __restrict__ wv,
              const int* __restrict__ p32, const int* __restrict__ i32,
              const int* __restrict__ t32,
              unsigned short* __restrict__ wsB,   // may be null
              unsigned* __restrict__ wsM,         // may be null
              unsigned short* __restrict__ wsX,   // may be null
              int num_nodes, int idx_words) {
  const int lane = threadIdx.x & 63;
  const unsigned wword = ((const unsigned*)wv)[lane];
  const int exw = (int)((wword >> 7) & 0xFFu);
  const bool w_bf16 = __popcll(__ballot(exw >= 96 && exw < 160)) >= 48;
  const unsigned xword = ((const unsigned*)xv)[lane];
  const int exx = (int)((xword >> 7) & 0xFFu);
  const bool x_bf16 = __popcll(__ballot(exx >= 96 && exx < 160)) >= 48;
  const bool idx64 = (p32[1] == 0);

  const int gs = gridDim.x * 256;
  const int g0 = blockIdx.x * 256 + threadIdx.x;

  if (wsB) {
    for (int i = g0; i < WFRAG; i += gs) {
      const int j  = i & 7;
      const int l  = (i >> 3) & 63;
      const int kt = (i >> 9) & 15;
      const int nt = i >> 13;
      const int k  = kt * 32 + (l >> 4) * 8 + j;
      const int n  = nt * 16 + (l & 15);
      float v;
      if (w_bf16) v = __bfloat162float(((const __hip_bfloat16*)wv)[k * 64 + n]);
      else        v = ((const float*)wv)[k * 64 + n];
      wsB[i] = f2bf(v);
    }
  }
  if (wsM) {
    const int E = idx64 ? (idx_words >> 1) : idx_words;
    for (int e = g0; e < E; e += gs) {
      const unsigned s = (unsigned)(idx64 ? i32[2 * e] : i32[e]);
      const unsigned r = (unsigned)(idx64 ? t32[2 * e] : t32[e]);
      wsM[e] = s | (r << 24);
    }
  }
  if (wsX && !x_bf16) {
    const f32x4* xf = (const f32x4*)xv;
    const int total8 = num_nodes * 8;
    for (int i = g0; i < total8; i += gs) {
      const f32x4 a = xf[i * 2 + 0];
      const f32x4 b = xf[i * 2 + 1];
      u16x8 o;
      __half h;
      h = __float2half(a[0]); o[0] = *reinterpret_cast<unsigned short*>(&h);
      h = __float2half(a[1]); o[1] = *reinterpret_cast<unsigned short*>(&h);
      h = __float2half(a[2]); o[2] = *reinterpret_cast<unsigned short*>(&h);
      h = __float2half(a[3]); o[3] = *reinterpret_cast<unsigned short*>(&h);
      h = __float2half(b[0]); o[4] = *reinterpret_cast<unsigned short*>(&h);
      h = __float2half(b[1]); o[5] = *reinterpret_cast<unsigned short*>(&h);
      h = __float2half(b[2]); o[6] = *reinterpret_cast<unsigned short*>(&h);
      h = __float2half(b[3]); o[7] = *reinterpret_cast<unsigned short*>(&h);
      ((u16x8*)wsX)[i] = o;
    }
  }
}

#define ACC_SW(accrow, r, vv)                                        \
  switch (r) {                                                       \
    case 0: accrow[0] += (vv); break; case 1: accrow[1] += (vv); break; \
    case 2: accrow[2] += (vv); break; case 3: accrow[3] += (vv); break; \
    case 4: accrow[4] += (vv); break; case 5: accrow[5] += (vv); break; \
    case 6: accrow[6] += (vv); break; default: accrow[7] += (vv); break; }

__global__ __launch_bounds__(THREADS, 6)
void rgcn_fused(const void* __restrict__ xv,
                const void* __restrict__ wv,
                const int* __restrict__ p32,
                const int* __restrict__ i32,
                const int* __restrict__ t32,
                const unsigned short* __restrict__ wsB,  // null -> W in LDS
                const unsigned* __restrict__ wsM,        // packed meta (or null)
                const unsigned short* __restrict__ wsX,  // fp16 x cache (or null)
                float* __restrict__ out,
                int num_nodes) {
  // aggS has NPB+1 rows: row NPB is the dump row for non-boundary stores.
  __hip_bfloat16* aggS = (__hip_bfloat16*)smem;                 // [NPB+1][LDA]
  __hip_bfloat16* wtS  = aggS + (NPB + 1) * LDA;                // only if !wsB
  char* tail = smem + (size_t)(NPB + 1) * LDA * 2 +
               (wsB ? 0 : (size_t)64 * LDA * 2);
  float*    invS  = (float*)tail;                               // [NPB]
  int*      ptrS  = (int*)(tail + 256);                         // [NPB+1]
  unsigned* eMeta = (unsigned*)(tail + 256 + 144);              // [MAXE]

  const int tid   = threadIdx.x;
  const int lane  = tid & 63;
  const int wvid  = tid >> 6;
  const int node0 = blockIdx.x * NPB;

  // runtime dtype / index-width detection (block-uniform)
  const unsigned xword = ((const unsigned*)xv)[lane];
  const int exf = (int)((xword >> 7) & 0xFFu);
  const bool x_bf16 = __popcll(__ballot(exf >= 96 && exf < 160)) >= 48;
  const bool idx64 = (p32[1] == 0);

  auto ldptr = [&](int n) -> int { return idx64 ? p32[2 * n] : p32[n]; };

  const int ntop   = min(node0 + NPB, num_nodes);
  const int e_lo   = ldptr(node0);
  const int ecount = ldptr(ntop) - e_lo;
  const bool staged = (ecount > 0 && ecount <= MAXE);

  for (int i = tid; i <= NPB; i += THREADS)
    ptrS[i] = ldptr(min(node0 + i, num_nodes));

  if (staged) {
    if (wsM) {
      // packed meta: one coalesced non-temporal dword per edge
      for (int e = tid; e < ecount; e += THREADS)
        eMeta[e] = __builtin_nontemporal_load(wsM + e_lo + e);
    } else {
      for (int e = tid; e < ecount; e += THREADS) {
        const int ge = e_lo + e;
        const unsigned s = (unsigned)(idx64 ? i32[2 * ge] : i32[ge]);
        const unsigned r = (unsigned)(idx64 ? t32[2 * ge] : t32[ge]);
        eMeta[e] = s | (r << 24);
      }
    }
  }

  if (!wsB) {  // fallback: stage W^T in LDS (rare; only if ws too small)
    if (x_bf16) {
      const __hip_bfloat16* wb = (const __hip_bfloat16*)wv;
      for (int i = tid; i < KDIM * 64; i += THREADS)
        wtS[(i & 63) * LDA + (i >> 6)] = wb[i];
    } else {
      const float* wf = (const float*)wv;
      for (int i = tid; i < KDIM * 64; i += THREADS)
        wtS[(i & 63) * LDA + (i >> 6)] = __float2bfloat16(wf[i]);
    }
  }

  __syncthreads();   // eMeta/ptrS staged

  // inverse degree (reads ptrS; consumed after later barriers)
  for (int i = tid; i < NPB; i += THREADS) {
    const int d = ptrS[i + 1] - ptrS[i];
    invS[i] = (d > 0 && node0 + i < num_nodes) ? 1.0f / (float)d : 0.0f;
  }

  // ---- stable counting sort of each deg-12 node's edges by relation ----
  if (staged) {
    for (int n = tid; n < NPB; n += THREADS) {
      const int b0 = ptrS[n] - e_lo;
      const int d  = ptrS[n + 1] - ptrS[n];
      if (d == 12) {
        unsigned mm[12];
        unsigned long long cnt = 0;
#pragma unroll
        for (int i = 0; i < 12; ++i) {
          mm[i] = eMeta[b0 + i];
          cnt += 1ull << ((mm[i] >> 24) * 4);
        }
        unsigned long long off = 0;
        unsigned run = 0;
#pragma unroll
        for (int r = 0; r < 8; ++r) {
          off |= (unsigned long long)run << (r * 4);
          run += (unsigned)((cnt >> (r * 4)) & 15ull);
        }
#pragma unroll
        for (int i = 0; i < 12; ++i) {
          const int sh = (int)(mm[i] >> 24) * 4;
          const unsigned slot = (unsigned)((off >> sh) & 15ull);
          off += 1ull << sh;
          eMeta[b0 + (int)slot] = mm[i];
        }
      }
    }
  }

  // ---- pre-zero agg tile (covers relations with no edges) ----
  {
    f32x4* z = (f32x4*)aggS;
    const f32x4 zero = {0.f, 0.f, 0.f, 0.f};
    const int nvec = (NPB + 1) * LDA * 2 / 16;   // 16B chunks
    for (int i = tid; i < nvec; i += THREADS) z[i] = zero;
  }

  __syncthreads();   // sorted eMeta + zeroed aggS visible

  const int c16 = lane & 15;
  const int qd  = lane >> 4;

  // ---- gather: wave owns 4 nodes (one group); quad qd owns node nlb+qd ----
  auto gather = [&](auto xp, auto loadrow) {
    const int nlb = wvid * 4;
    const int eq0 = ptrS[nlb + qd] - e_lo;          // quad-uniform per lane
    const int dq  = ptrS[nlb + qd + 1] - e_lo - eq0;
    const bool okfast = staged && (node0 + nlb + 3 < num_nodes) &&
                        (__ballot(dq == 12) == ~0ull);
    if (okfast) {
      // phase 1: sorted edge meta (quad-broadcast LDS reads)
      unsigned m[12];
      unsigned rr[12];
#pragma unroll
      for (int j = 0; j < 12; ++j) m[j] = eMeta[eq0 + j];
#pragma unroll
      for (int j = 0; j < 12; ++j) rr[j] = m[j] >> 24;
      // phase 2: 12 independent row loads, all in flight
      f32x4 v[12];
#pragma unroll
      for (int j = 0; j < 12; ++j)
        v[j] = loadrow((int)(m[j] & 0x00FFFFFFu), c16);
      // phase 3: run-boundary flush (sorted rels -> runs are contiguous)
      unsigned short* nodeP =
          (unsigned short*)(aggS + (size_t)(nlb + qd) * LDA) + 4 * c16;
      unsigned short* dumpP =
          (unsigned short*)(aggS + (size_t)NPB * LDA) + qd * 136 + 4 * c16;
      f32x4 A = {0.f, 0.f, 0.f, 0.f};
#pragma unroll
      for (int j = 0; j < 12; ++j) {
        A += v[j];
        const bool b = (j == 11) || (rr[j] != rr[j + 1 < 12 ? j + 1 : 11]);
        ushort4 bb;
        bb.x = f2bf(A[0]); bb.y = f2bf(A[1]);
        bb.z = f2bf(A[2]); bb.w = f2bf(A[3]);
        unsigned short* dst = b ? (nodeP + (rr[j] << 6)) : dumpP;
        *(ushort4*)dst = bb;
        A = b ? (f32x4){0.f, 0.f, 0.f, 0.f} : A;
      }
    } else {
      // generic: full wave per node, lane = channel, wave-uniform switch
#pragma unroll
      for (int t = 0; t < 4; ++t) {
        const int nl = nlb + t;
        float a[8] = {0.f, 0.f, 0.f, 0.f, 0.f, 0.f, 0.f, 0.f};
        if (node0 + nl < num_nodes) {
          const int e0 = ptrS[nl] - e_lo, e1 = ptrS[nl + 1] - e_lo;
          for (int e = e0; e < e1; ++e) {
            unsigned mm;
            if (staged) mm = eMeta[e];
            else if (wsM) mm = wsM[e_lo + e];
            else {
              const int ge = e_lo + e;
              mm = (unsigned)(idx64 ? i32[2 * ge] : i32[ge]) |
                   ((unsigned)(idx64 ? t32[2 * ge] : t32[ge]) << 24);
            }
            const float vv = xp((size_t)(mm & 0x00FFFFFFu) * 64 + lane);
            const int r = __builtin_amdgcn_readfirstlane((int)(mm >> 24));
            ACC_SW(a, r, vv)
          }
        }
#pragma unroll
        for (int r = 0; r < 8; ++r)
          aggS[(size_t)nl * LDA + r * 64 + lane] = __float2bfloat16(a[r]);
      }
    }
  };

  if (!x_bf16 && wsX) {
    // fp16 x-cache path: 128-B rows, ushort4/lane + 4x cvt
    auto xp = [&](size_t i) -> float { return h2f(wsX[i]); };
    auto lr = [&](int src, int c) -> f32x4 {
      const ushort4 u = ((const ushort4*)wsX)[(size_t)src * 16 + c];
      f32x4 f;
      f[0] = h2f(u.x); f[1] = h2f(u.y); f[2] = h2f(u.z); f[3] = h2f(u.w);
      return f;
    };
    gather(xp, lr);
  } else if (x_bf16) {
    auto xp = [&](size_t i) -> float {
      const unsigned short u = ((const unsigned short*)xv)[i];
      return __uint_as_float((unsigned)u << 16);
    };
    auto lr = [&](int src, int c) -> f32x4 {
      const ushort4 u = ((const ushort4*)xv)[(size_t)src * 16 + c];
      f32x4 f;
      f[0] = __uint_as_float((unsigned)(unsigned short)u.x << 16);
      f[1] = __uint_as_float((unsigned)(unsigned short)u.y << 16);
      f[2] = __uint_as_float((unsigned)(unsigned short)u.z << 16);
      f[3] = __uint_as_float((unsigned)(unsigned short)u.w << 16);
      return f;
    };
    gather(xp, lr);
  } else {
    auto xp = [&](size_t i) -> float { return ((const float*)xv)[i]; };
    auto lr = [&](int src, int c) -> f32x4 {
      return ((const f32x4*)xv)[(size_t)src * 16 + c];
    };
    gather(xp, lr);
  }

  __syncthreads();

  // ---- MFMA: out_tile[32x64] = agg[32x512] @ Wcat[512x64] ----
  // 8 waves: mt = wvid>>2 (0..1 row-tiles), nt = wvid&3 (0..3 col-tiles)
  const int mt = wvid >> 2;
  const int nt = wvid & 3;
  const int mi = lane & 15;
  const int q4 = lane >> 4;
  const __hip_bfloat16* ap = aggS + (size_t)(mt * 16 + mi) * LDA + q4 * 8;
  f32x4 c0 = {0.f, 0.f, 0.f, 0.f};
  if (wsB) {
    const bf16x8* B = (const bf16x8*)wsB;
#pragma unroll
    for (int kt = 0; kt < KDIM / 32; ++kt) {
      const bf16x8 a = *(const bf16x8*)(ap + kt * 32);
      const bf16x8 b = B[(nt * 16 + kt) * 64 + lane];
      c0 = __builtin_amdgcn_mfma_f32_16x16x32_bf16(a, b, c0, 0, 0, 0);
    }
  } else {
    const __hip_bfloat16* bp = wtS + (size_t)(nt * 16 + mi) * LDA + q4 * 8;
#pragma unroll
    for (int kt = 0; kt < KDIM / 32; ++kt) {
      const bf16x8 a = *(const bf16x8*)(ap + kt * 32);
      const bf16x8 b = *(const bf16x8*)(bp + kt * 32);
      c0 = __builtin_amdgcn_mfma_f32_16x16x32_bf16(a, b, c0, 0, 0, 0);
    }
  }

  // D layout: col = lane&15, row = q4*4 + reg -> non-temporal fp32 stores
  // (write-once stream; keep it out of L2 so the x-cache stays resident)
#pragma unroll
  for (int i = 0; i < 4; ++i) {
    const int row  = q4 * 4 + i;
    const int nl   = mt * 16 + row;
    const int node = node0 + nl;
    if (node < num_nodes) {
      const float v = c0[i] * invS[nl];
      __builtin_nontemporal_store(v, &out[(size_t)node * 64 + nt * 16 + mi]);
    }
  }
}

extern "C" void kernel_launch(void* const* d_in, const int* in_sizes, int n_in,
                              void* d_out, int out_size, void* d_ws, size_t ws_size,
                              hipStream_t stream) {
  const void* x   = d_in[0];
  const void* w   = d_in[1];
  const int*  ptr = (const int*)d_in[2];
  const int*  idx = (const int*)d_in[3];
  const int*  et  = (const int*)d_in[4];
  float*      out = (float*)d_out;

  const int num_nodes = in_sizes[0] / 64;   // x is [N, 64] fp32
  const int idx_words = in_sizes[3];        // idx buffer in 4-byte words

  // ws layout: [wsB 64KB][wsM idx_words*4 B][wsX N*128 B], 16B-aligned joints
  const size_t needW = (size_t)WFRAG * sizeof(unsigned short);           // 64 KB
  const size_t offM  = (needW + 15) & ~(size_t)15;
  const size_t needM = offM + (size_t)idx_words * 4;
  const size_t offX  = (needM + 15) & ~(size_t)15;
  const size_t needX = offX + (size_t)num_nodes * 64 * 2;

  const bool useWs = (d_ws != nullptr) && (ws_size >= needW);
  const bool useM  = (d_ws != nullptr) && (ws_size >= needM);
  const bool useX  = (d_ws != nullptr) && (ws_size >= needX);
  unsigned short* wsB = useWs ? (unsigned short*)d_ws : nullptr;
  unsigned*       wsM = useM ? (unsigned*)((char*)d_ws + offM) : nullptr;
  unsigned short* wsX = useX ? (unsigned short*)((char*)d_ws + offX) : nullptr;

  if (useWs)
    pack_all<<<2048, 256, 0, stream>>>(x, w, ptr, idx, et, wsB, wsM, wsX,
                                       num_nodes, idx_words);

  const size_t lds_bytes = (size_t)(NPB + 1) * LDA * 2 +
                           (useWs ? 0 : (size_t)64 * LDA * 2) +
                           256 + 144 + (size_t)MAXE * 4;

  hipFuncSetAttribute((const void*)rgcn_fused,
                      hipFuncAttributeMaxDynamicSharedMemorySize,
                      (int)lds_bytes);

  const int nblocks = (num_nodes + NPB - 1) / NPB;
  rgcn_fused<<<nblocks, THREADS, lds_bytes, stream>>>(x, w, ptr, idx, et, wsB,
                                                      wsM, wsX, out, num_nodes);
}